// Round 7
// baseline (128.555 us; speedup 1.0000x reference)
//
#include <hip/hip_runtime.h>
#include <stdint.h>

#define NB     65536
#define BATCH  4
#define TOPN   1000
#define MMAX   2048
#define NTILE  (MMAX / 64)                 // 32
#define NPAIRS (NTILE * (NTILE + 1) / 2)   // 528
#define PBLK   (NPAIRS / 16)               // 33 blocks/image, 16 tiles (waves) each
#define CAP    128                         // per-prep-block candidate region
#define KSUP   8
#define UNC    128
#define THRESH 0.974f
#define NEGV   (-1e9f)
#define NMS_T  0.7f

// ws layout (bytes):
//   0      : ctrs u32[16] ([0..3]=n, [8..11]=fallback flag, [12..15]=ticket)
//   64     : cnt_blk  u32[256]   per prep-block true candidate count
//   1088   : keys_raw u64[256*CAP]
//   263232 : sboxes   float4[B*MMAX]  rank-sorted, clipped, non-offset
//   394304 : slev     i32[B*MMAX]
//   427072 : cnt2     u32[B*MMAX]  per-candidate suppressor counts (zeroed by k_rank)
//   459840 : suplist  i32[B*MMAX*KSUP]
#define OFF_CBLK   64
#define OFF_KRAW   1088
#define OFF_SBOX   263232
#define OFF_SLEV   394304
#define OFF_CNT2   427072
#define OFF_SUP    459840

__device__ __forceinline__ void decode_box(const float4* __restrict__ anchors4,
                                           const float4* __restrict__ deltas4,
                                           int b, int i, float wmax, float hmax,
                                           float& x1, float& y1, float& x2, float& y2) {
  float4 a = anchors4[i];
  float4 d = deltas4[(size_t)b * NB + i];
  float ws = a.z - a.x + 1.0f;
  float hs = a.w - a.y + 1.0f;
  float cx = a.x + 0.5f * ws;
  float cy = a.y + 0.5f * hs;
  float pcx = d.x * ws + cx;
  float pcy = d.y * hs + cy;
  float pw = expf(d.z) * ws;
  float ph = expf(d.w) * hs;
  x1 = pcx - 0.5f * pw; y1 = pcy - 0.5f * ph;
  x2 = pcx + 0.5f * pw; y2 = pcy + 0.5f * ph;
  x1 = fminf(fmaxf(x1, 0.0f), wmax);
  y1 = fminf(fmaxf(y1, 0.0f), hmax);
  x2 = fminf(fmaxf(x2, 0.0f), wmax);
  y2 = fminf(fmaxf(y2, 0.0f), hmax);
}

// block-wide exclusive scan, 256 threads (4 waves). wsum: u32[5].
__device__ __forceinline__ uint32_t blockscan(uint32_t v, volatile uint32_t* wsum,
                                              int tid, uint32_t* total) {
  __syncthreads();
  int lane = tid & 63, wid = tid >> 6;
  uint32_t x = v;
  for (int off = 1; off < 64; off <<= 1) {
    uint32_t u = __shfl_up(x, off, 64);
    if (lane >= off) x += u;
  }
  if (lane == 63) wsum[wid] = x;
  __syncthreads();
  if (tid == 0) {
    uint32_t run = 0;
    for (int w = 0; w < 4; ++w) { uint32_t t = wsum[w]; wsum[w] = run; run += t; }
    wsum[4] = run;
  }
  __syncthreads();
  *total = wsum[4];
  return x - v + wsum[wid];
}

// pure score-threshold scan: float4 loads, per-block private emission (no decode, no atomics)
__global__ __launch_bounds__(256) void k_prep(const float* __restrict__ scores,
                                              unsigned long long* __restrict__ keys_raw,
                                              uint32_t* __restrict__ cnt_blk) {
  const int b = blockIdx.x >> 6;       // 64 blocks / image
  const int blk = blockIdx.x & 63;     // 1024 scores / block
  const int tid = threadIdx.x;
  __shared__ uint32_t wsum[5];
  const float4* s4 = (const float4*)scores + (size_t)b * (NB / 4) + (size_t)blk * 256 + tid;
  float4 s = *s4;
  float sc4[4] = {s.x, s.y, s.z, s.w};
  uint32_t cmask = 0, ccount = 0;
#pragma unroll
  for (int k = 0; k < 4; ++k)
    if (sc4[k] >= THRESH) { cmask |= (1u << k); ccount++; }
  uint32_t total;
  uint32_t p = blockscan(ccount, wsum, tid, &total);
  if (tid == 0) cnt_blk[blockIdx.x] = total;  // TRUE count (k_rank detects >CAP)
  unsigned long long* dst = keys_raw + (size_t)blockIdx.x * CAP;
#pragma unroll
  for (int k = 0; k < 4; ++k) {
    if (cmask & (1u << k)) {
      if (p < (uint32_t)CAP) {
        int i = (blk << 10) + (tid << 2) + k;
        dst[p] = ((unsigned long long)(~__float_as_uint(sc4[k])) << 32) | (uint32_t)i;
      }
      p++;
    }
  }
}

// gather per-block counts -> bases; compact keys to LDS; rank-by-counting (broadcast
// windows); decode+write sorted boxes/levels; publish ctrs; zero cnt2 + ticket.
__global__ __launch_bounds__(256) void k_rank(const uint32_t* __restrict__ cnt_blk,
                                              const unsigned long long* __restrict__ keys_raw,
                                              const float4* __restrict__ deltas4,
                                              const float4* __restrict__ anchors4,
                                              const float* __restrict__ im_info,
                                              const int* __restrict__ ids,
                                              uint32_t* ctrs,
                                              float4* sboxes, int* slev,
                                              uint32_t* cnt2) {
  const int b = blockIdx.y;
  const int r = blockIdx.x;            // 0..31: owns candidates [r*64, r*64+64)
  const int tid = threadIdx.x;
  const int lane = tid & 63, wid = tid >> 6;
  __shared__ unsigned long long sk[MMAX];   // 16 KB
  __shared__ uint32_t scnt[64], sbs[64];
  __shared__ uint32_t psum[256];
  __shared__ uint32_t meta[2];              // [0]=n_capped_sum [1]=ovflag

  if (tid < 64) {
    uint32_t c = cnt_blk[b * 64 + tid];
    uint32_t cc = min(c, (uint32_t)CAP);
    scnt[tid] = cc;
    uint32_t x = cc;
    for (int off = 1; off < 64; off <<= 1) {
      uint32_t u = __shfl_up(x, off, 64);
      if (lane >= off) x += u;
    }
    sbs[tid] = x - cc;
    unsigned long long ov = __ballot(c > (uint32_t)CAP);
    if (tid == 63) { meta[0] = x; meta[1] = (ov != 0ULL) ? 1u : 0u; }
  }
  __syncthreads();
  uint32_t nsum = meta[0];
  int n = min((int)nsum, MMAX);
  uint32_t flag = meta[1] | ((nsum > (uint32_t)MMAX) ? 1u : 0u);
  if (r == 0 && tid == 0) {
    ctrs[b] = (uint32_t)n;
    ctrs[8 + b] = flag;
    ctrs[12 + b] = 0u;   // ticket counter for k_po (prior dispatch -> race-free)
  }
  if (tid < 64) cnt2[(size_t)b * MMAX + r * 64 + tid] = 0u;  // 32 blocks x 64 = MMAX
  // compact: thread group of 4 per source block
  {
    int k = tid >> 2, q = tid & 3;
    uint32_t cb = sbs[k], cc = scnt[k];
    const unsigned long long* src = keys_raw + ((size_t)b * 64 + k) * CAP;
    for (uint32_t o = q; o < cc; o += 4) {
      uint32_t d = cb + o;
      if (d < (uint32_t)MMAX) sk[d] = src[o];
    }
  }
  for (int i = tid; i < MMAX; i += 256) if (i >= n) sk[i] = ~0ULL;
  __syncthreads();
  // rank my 64 candidates: each wave counts one 512-key window (broadcast reads)
  int c = r * 64 + lane;
  uint32_t partial = 0;
  if (c < n) {
    unsigned long long myk = sk[c];
    const ulonglong2* p2 = (const ulonglong2*)(sk + (size_t)wid * 512);
    for (int it = 0; it < 256; it += 4) {
      ulonglong2 a = p2[it], bq = p2[it + 1], cq = p2[it + 2], dq = p2[it + 3];
      partial += (uint32_t)(a.x < myk) + (uint32_t)(a.y < myk) +
                 (uint32_t)(bq.x < myk) + (uint32_t)(bq.y < myk) +
                 (uint32_t)(cq.x < myk) + (uint32_t)(cq.y < myk) +
                 (uint32_t)(dq.x < myk) + (uint32_t)(dq.y < myk);
    }
  }
  psum[wid * 64 + lane] = partial;
  __syncthreads();
  if (tid < 64) {
    int cc = r * 64 + tid;
    if (cc < n) {
      uint32_t rank = psum[tid] + psum[64 + tid] + psum[128 + tid] + psum[192 + tid];
      if (rank < (uint32_t)MMAX) {
        unsigned long long key = sk[cc];
        int i = (int)(uint32_t)key;
        float wmax = im_info[b * 3 + 1] - 1.0f;
        float hmax = im_info[b * 3 + 0] - 1.0f;
        float x1, y1, x2, y2;
        decode_box(anchors4, deltas4, b, i, wmax, hmax, x1, y1, x2, y2);
        sboxes[(size_t)b * MMAX + rank] = make_float4(x1, y1, x2, y2);
        slev[(size_t)b * MMAX + rank] = ids[i];
      }
    }
  }
}

// 1024-thread (16-wave) scan
__device__ __forceinline__ uint32_t scan_pair(uint32_t pairsum, volatile uint32_t* wsum,
                                              int tid, uint32_t* total_out) {
  int lane = tid & 63, wid = tid >> 6;
  uint32_t v = pairsum;
  for (int off = 1; off < 64; off <<= 1) {
    uint32_t u = __shfl_up(v, off, 64);
    if (lane >= off) v += u;
  }
  if (lane == 63) wsum[wid] = v;
  __syncthreads();
  if (tid == 0) {
    uint32_t run = 0;
    for (int w = 0; w < 16; ++w) { uint32_t t = wsum[w]; wsum[w] = run; run += t; }
    wsum[16] = run;
  }
  __syncthreads();
  uint32_t incl = v + wsum[wid];
  *total_out = wsum[16];
  return incl - pairsum;
}

// fused pairs + (tail-block) resolve/output/fallback.
// 33 blocks/image x 1024 threads; wave w handles tile blkL*16+w; last block to
// finish its image (device-scope ticket) performs the k_out body.
__global__ __launch_bounds__(1024) void k_po(const float* __restrict__ scores,
                                             const float4* __restrict__ deltas4,
                                             const float4* __restrict__ anchors4,
                                             const float* __restrict__ im_info,
                                             const int* __restrict__ ids,
                                             uint32_t* ctrs,
                                             const float4* __restrict__ sboxes,
                                             const int* __restrict__ slev,
                                             uint32_t* cnt2, int* suplist,
                                             float* __restrict__ out) {
  const int b = blockIdx.y;
  const int blkL = blockIdx.x;     // 0..32
  const int tid = threadIdx.x;
  const int lane = tid & 63, wid = tid >> 6;
  __shared__ float4 ib[16][64];    // per-wave I-tiles
  __shared__ int il[16][64];
  __shared__ int swin;
  int n = min((int)ctrs[b], MMAX);

  // ---------- pairs phase (tile body verbatim; one tile per wave) ----------
  {
    int p = blkL * 16 + wid;       // 0..527
    int tj = (int)((sqrtf(8.0f * (float)p + 1.0f) - 1.0f) * 0.5f);
    while ((tj + 1) * (tj + 2) / 2 <= p) ++tj;
    while (tj * (tj + 1) / 2 > p) --tj;
    int ti = p - tj * (tj + 1) / 2;
    bool act = (tj * 64 < n);
    int ii = ti * 64 + lane;
    if (act && ii < n) {
      ib[wid][lane] = sboxes[(size_t)b * MMAX + ii];
      il[wid][lane] = slev[(size_t)b * MMAX + ii];
    } else {
      il[wid][lane] = -1;
    }
    int j = tj * 64 + lane;
    float4 J = make_float4(0.f, 0.f, 0.f, 0.f);
    int jl = -2;
    float aj = 0.0f;
    if (act && j < n) {
      J = sboxes[(size_t)b * MMAX + j];
      jl = slev[(size_t)b * MMAX + j];
      aj = (J.z - J.x) * (J.w - J.y);
    }
    __syncthreads();
    if (act && j < n) {
      int imax = (ti == tj) ? lane : 64;  // diagonal: only i<j
      for (int k = 0; k < imax; ++k) {
        if (il[wid][k] != jl) continue;
        float4 I = ib[wid][k];
        float xx1 = fmaxf(I.x, J.x), yy1 = fmaxf(I.y, J.y);
        float xx2 = fminf(I.z, J.z), yy2 = fminf(I.w, J.w);
        float inter = fmaxf(xx2 - xx1, 0.0f) * fmaxf(yy2 - yy1, 0.0f);
        float ai = (I.z - I.x) * (I.w - I.y);
        float iou = inter / fmaxf((ai + aj) - inter, 1e-6f);
        if (iou > NMS_T) {
          uint32_t s = atomicAdd(&cnt2[(size_t)b * MMAX + j], 1u);
          if (s < (uint32_t)KSUP) suplist[((size_t)b * MMAX + j) * KSUP + s] = ti * 64 + k;
          else atomicOr(&ctrs[8 + b], 1u);  // suppressor-list overflow -> fallback
        }
      }
    }
  }

  // ---------- ticket: last block of this image becomes the output block ----------
  __threadfence();      // release pairs-phase writes (device scope)
  __syncthreads();
  if (tid == 0) swin = ((int)atomicAdd(&ctrs[12 + b], 1u) == PBLK - 1) ? 1 : 0;
  __syncthreads();
  if (!swin) return;
  __threadfence();      // acquire siblings' writes

  // ---------- k_out body (verbatim; cross-block data via agent atomic loads) ----------
  __shared__ uint8_t kept[MMAX];
  __shared__ uint32_t wsum[17];
  __shared__ uint16_t unc[UNC];
  __shared__ int supld[UNC][KSUP];
  __shared__ uint8_t supn[UNC];
  int j0 = tid * 2, j1 = tid * 2 + 1;
  uint32_t c0 = (j0 < n) ? __hip_atomic_load(&cnt2[(size_t)b * MMAX + j0],
                                             __ATOMIC_RELAXED, __HIP_MEMORY_SCOPE_AGENT) : 0u;
  uint32_t c1 = (j1 < n) ? __hip_atomic_load(&cnt2[(size_t)b * MMAX + j1],
                                             __ATOMIC_RELAXED, __HIP_MEMORY_SCOPE_AGENT) : 0u;
  kept[j0] = (j0 < n && c0 == 0u) ? 1 : 0;
  kept[j1] = (j1 < n && c1 == 0u) ? 1 : 0;
  uint32_t u0 = (j0 < n && c0 > 0u) ? 1u : 0u;
  uint32_t u1 = (j1 < n && c1 > 0u) ? 1u : 0u;
  uint32_t tot_unc;
  uint32_t base = scan_pair(u0 + u1, wsum, tid, &tot_unc);
  if (u0) {
    uint32_t p = base;
    if (p < UNC) {
      int m = (int)min(c0, (uint32_t)KSUP);
      unc[p] = (uint16_t)j0; supn[p] = (uint8_t)m;
      for (int s = 0; s < m; ++s)
        supld[p][s] = __hip_atomic_load(&suplist[((size_t)b * MMAX + j0) * KSUP + s],
                                        __ATOMIC_RELAXED, __HIP_MEMORY_SCOPE_AGENT);
    }
  }
  if (u1) {
    uint32_t p = base + u0;
    if (p < UNC) {
      int m = (int)min(c1, (uint32_t)KSUP);
      unc[p] = (uint16_t)j1; supn[p] = (uint8_t)m;
      for (int s = 0; s < m; ++s)
        supld[p][s] = __hip_atomic_load(&suplist[((size_t)b * MMAX + j1) * KSUP + s],
                                        __ATOMIC_RELAXED, __HIP_MEMORY_SCOPE_AGENT);
    }
  }
  __syncthreads();
  if (tid < 64) {  // wave 0: exact greedy resolution in ascending rank order
    int nu = (int)min(tot_unc, (uint32_t)UNC);
    for (int u = 0; u < nu; ++u) {
      int m = (int)supn[u];
      int pred = (tid < m) ? (int)kept[supld[u][tid]] : 0;
      unsigned long long bal = __ballot(pred);
      if (tid == 0) kept[unc[u]] = (bal == 0ULL) ? 1 : 0;
    }
  }
  __syncthreads();
  uint32_t k0 = kept[j0], k1 = kept[j1];
  uint32_t total;
  uint32_t pbase = scan_pair(k0 + k1, wsum, tid, &total);
  if (k0 && pbase < (uint32_t)TOPN) {
    float4 bx = sboxes[(size_t)b * MMAX + j0];
    size_t o = ((size_t)b * TOPN + pbase) * 5;
    out[o] = (float)b; out[o+1] = bx.x; out[o+2] = bx.y; out[o+3] = bx.z; out[o+4] = bx.w;
  }
  if (k1) {
    uint32_t p = pbase + k0;
    if (p < (uint32_t)TOPN) {
      float4 bx = sboxes[(size_t)b * MMAX + j1];
      size_t o = ((size_t)b * TOPN + p) * 5;
      out[o] = (float)b; out[o+1] = bx.x; out[o+2] = bx.y; out[o+3] = bx.z; out[o+4] = bx.w;
    }
  }
  for (int t = tid; t < TOPN; t += 1024) {
    if ((uint32_t)t >= total) {
      size_t o = ((size_t)b * TOPN + t) * 5;
      out[o] = (float)b; out[o+1] = 0.0f; out[o+2] = 0.0f; out[o+3] = 0.0f; out[o+4] = 0.0f;
    }
  }

  uint32_t gflag = __hip_atomic_load(&ctrs[8 + b], __ATOMIC_RELAXED, __HIP_MEMORY_SCOPE_AGENT);
  bool needFB = (gflag != 0u) || (total < (uint32_t)TOPN) || (tot_unc > (uint32_t)UNC);
  if (!needFB) return;

  // ---------- exact brute-force fallback (block-uniform path) ----------
  __shared__ uint32_t mask[NB / 32];
  __shared__ float rv[1024];
  __shared__ int ri[1024];
  __shared__ float fm[16];
  const float wmax = im_info[b * 3 + 1] - 1.0f;
  const float hmax = im_info[b * 3 + 0] - 1.0f;
  __syncthreads();
  float mx = 0.0f;
  for (int i = tid; i < NB; i += 1024) {
    float x1, y1, x2, y2;
    decode_box(anchors4, deltas4, b, i, wmax, hmax, x1, y1, x2, y2);
    mx = fmaxf(mx, fmaxf(fmaxf(x1, y1), fmaxf(x2, y2)));
  }
  for (int o = 32; o > 0; o >>= 1) mx = fmaxf(mx, __shfl_xor(mx, o, 64));
  if ((tid & 63) == 0) fm[tid >> 6] = mx;
  __syncthreads();
  if (tid == 0) {
    float m = fm[0];
    for (int w = 1; w < 16; ++w) m = fmaxf(m, fm[w]);
    fm[0] = m;
  }
  for (int i = tid; i < NB / 32; i += 1024) mask[i] = 0u;
  __syncthreads();
  float max_c = fm[0] + 1.0f;
  for (int it = 0; it < TOPN; ++it) {
    float bv = -3e38f; int bi = 0x7fffffff;
    for (int i = tid; i < NB; i += 1024) {
      bool sup = (mask[i >> 5] >> (i & 31)) & 1u;
      float v = sup ? NEGV : scores[(size_t)b * NB + i];
      if (v > bv || (v == bv && i < bi)) { bv = v; bi = i; }
    }
    rv[tid] = bv; ri[tid] = bi;
    __syncthreads();
    for (int s = 512; s > 0; s >>= 1) {
      if (tid < s) {
        float v2 = rv[tid + s]; int i2 = ri[tid + s];
        if (v2 > rv[tid] || (v2 == rv[tid] && i2 < ri[tid])) { rv[tid] = v2; ri[tid] = i2; }
      }
      __syncthreads();
    }
    int ii = ri[0]; float vv = rv[0];
    bool valid = vv > NEGV * 0.5f;
    if (!valid) {
      if (tid == 0) {
        size_t o = ((size_t)b * TOPN + it) * 5;
        out[o] = (float)b; out[o+1] = 0; out[o+2] = 0; out[o+3] = 0; out[o+4] = 0;
      }
      __syncthreads();
      continue;
    }
    float x1, y1, x2, y2;
    decode_box(anchors4, deltas4, b, ii, wmax, hmax, x1, y1, x2, y2);
    int lv = ids[ii];
    float off = (float)lv * max_c;
    float s0 = x1 + off, s1 = y1 + off, s2 = x2 + off, s3 = y2 + off;
    float a1 = (s2 - s0) * (s3 - s1);
    if (tid == 0) {
      size_t o = ((size_t)b * TOPN + it) * 5;
      out[o] = (float)b; out[o+1] = x1; out[o+2] = y1; out[o+3] = x2; out[o+4] = y2;
    }
    for (int j = tid; j < NB; j += 1024) {
      if ((mask[j >> 5] >> (j & 31)) & 1u) continue;
      if (ids[j] != lv) continue;  // cross-level IoU exactly 0 under offset geometry
      float bx1, by1, bx2, by2;
      decode_box(anchors4, deltas4, b, j, wmax, hmax, bx1, by1, bx2, by2);
      float t0 = bx1 + off, t1 = by1 + off, t2 = bx2 + off, t3 = by2 + off;
      float xx1 = fmaxf(s0, t0), yy1 = fmaxf(s1, t1);
      float xx2 = fminf(s2, t2), yy2 = fminf(s3, t3);
      float inter = fmaxf(xx2 - xx1, 0.0f) * fmaxf(yy2 - yy1, 0.0f);
      float a2r = (t2 - t0) * (t3 - t1);
      float iou = inter / fmaxf(a1 + a2r - inter, 1e-6f);
      if (iou > NMS_T) atomicOr(&mask[j >> 5], 1u << (j & 31));
    }
    if (tid == 0) atomicOr(&mask[ii >> 5], 1u << (ii & 31));
    __syncthreads();
  }
}

extern "C" void kernel_launch(void* const* d_in, const int* in_sizes, int n_in,
                              void* d_out, int out_size, void* d_ws, size_t ws_size,
                              hipStream_t stream) {
  const float*  scores   = (const float*)d_in[0];
  const float4* deltas4  = (const float4*)d_in[1];
  const float4* anchors4 = (const float4*)d_in[2];
  const float*  im_info  = (const float*)d_in[3];
  const int*    ids      = (const int*)d_in[4];
  float* out = (float*)d_out;

  char* ws = (char*)d_ws;
  uint32_t*           ctrs     = (uint32_t*)ws;
  uint32_t*           cnt_blk  = (uint32_t*)(ws + OFF_CBLK);
  unsigned long long* keys_raw = (unsigned long long*)(ws + OFF_KRAW);
  float4*             sboxes   = (float4*)(ws + OFF_SBOX);
  int*                slev     = (int*)(ws + OFF_SLEV);
  uint32_t*           cnt2     = (uint32_t*)(ws + OFF_CNT2);
  int*                suplist  = (int*)(ws + OFF_SUP);

  hipLaunchKernelGGL(k_prep, dim3(64 * BATCH), dim3(256), 0, stream,
                     scores, keys_raw, cnt_blk);
  hipLaunchKernelGGL(k_rank, dim3(NTILE, BATCH), dim3(256), 0, stream,
                     cnt_blk, keys_raw, deltas4, anchors4, im_info, ids,
                     ctrs, sboxes, slev, cnt2);
  hipLaunchKernelGGL(k_po, dim3(PBLK, BATCH), dim3(1024), 0, stream,
                     scores, deltas4, anchors4, im_info, ids, ctrs,
                     sboxes, slev, cnt2, suplist, out);
}

// Round 8
// 104.130 us; speedup vs baseline: 1.2346x; 1.2346x over previous
//
#include <hip/hip_runtime.h>
#include <stdint.h>

#define NB     65536
#define BATCH  4
#define TOPN   1000
#define MMAX   2048
#define NTILE  (MMAX / 64)                 // 32
#define NPAIRS (NTILE * (NTILE + 1) / 2)   // 528
#define PBLK   (NPAIRS / 16)               // 33 blocks/image, 16 tiles (waves) each
#define CAP    128                         // per-prep-block candidate region
#define KSUP   8
#define UNC    128
#define THRESH 0.974f
#define NEGV   (-1e9f)
#define NMS_T  0.7f

// ws layout (bytes):
//   0      : ctrs u32[16] ([0..3]=n, [8..11]=fallback flag, [12..15]=ticket)
//   64     : cnt_blk  u32[256]   per prep-block true candidate count
//   1088   : keys_raw u64[256*CAP]
//   263232 : sboxes   float4[B*MMAX]  rank-sorted, clipped, non-offset
//   394304 : slev     i32[B*MMAX]
//   427072 : cnt2     u32[B*MMAX]  per-candidate suppressor counts (zeroed by k_rank)
//   459840 : suplist  i32[B*MMAX*KSUP]
#define OFF_CBLK   64
#define OFF_KRAW   1088
#define OFF_SBOX   263232
#define OFF_SLEV   394304
#define OFF_CNT2   427072
#define OFF_SUP    459840

__device__ __forceinline__ void decode_box(const float4* __restrict__ anchors4,
                                           const float4* __restrict__ deltas4,
                                           int b, int i, float wmax, float hmax,
                                           float& x1, float& y1, float& x2, float& y2) {
  float4 a = anchors4[i];
  float4 d = deltas4[(size_t)b * NB + i];
  float ws = a.z - a.x + 1.0f;
  float hs = a.w - a.y + 1.0f;
  float cx = a.x + 0.5f * ws;
  float cy = a.y + 0.5f * hs;
  float pcx = d.x * ws + cx;
  float pcy = d.y * hs + cy;
  float pw = expf(d.z) * ws;
  float ph = expf(d.w) * hs;
  x1 = pcx - 0.5f * pw; y1 = pcy - 0.5f * ph;
  x2 = pcx + 0.5f * pw; y2 = pcy + 0.5f * ph;
  x1 = fminf(fmaxf(x1, 0.0f), wmax);
  y1 = fminf(fmaxf(y1, 0.0f), hmax);
  x2 = fminf(fmaxf(x2, 0.0f), wmax);
  y2 = fminf(fmaxf(y2, 0.0f), hmax);
}

// block-wide exclusive scan, 256 threads (4 waves). wsum: u32[5].
__device__ __forceinline__ uint32_t blockscan(uint32_t v, volatile uint32_t* wsum,
                                              int tid, uint32_t* total) {
  __syncthreads();
  int lane = tid & 63, wid = tid >> 6;
  uint32_t x = v;
  for (int off = 1; off < 64; off <<= 1) {
    uint32_t u = __shfl_up(x, off, 64);
    if (lane >= off) x += u;
  }
  if (lane == 63) wsum[wid] = x;
  __syncthreads();
  if (tid == 0) {
    uint32_t run = 0;
    for (int w = 0; w < 4; ++w) { uint32_t t = wsum[w]; wsum[w] = run; run += t; }
    wsum[4] = run;
  }
  __syncthreads();
  *total = wsum[4];
  return x - v + wsum[wid];
}

// pure score-threshold scan: float4 loads, per-block private emission (no decode, no atomics)
__global__ __launch_bounds__(256) void k_prep(const float* __restrict__ scores,
                                              unsigned long long* __restrict__ keys_raw,
                                              uint32_t* __restrict__ cnt_blk) {
  const int b = blockIdx.x >> 6;       // 64 blocks / image
  const int blk = blockIdx.x & 63;     // 1024 scores / block
  const int tid = threadIdx.x;
  __shared__ uint32_t wsum[5];
  const float4* s4 = (const float4*)scores + (size_t)b * (NB / 4) + (size_t)blk * 256 + tid;
  float4 s = *s4;
  float sc4[4] = {s.x, s.y, s.z, s.w};
  uint32_t cmask = 0, ccount = 0;
#pragma unroll
  for (int k = 0; k < 4; ++k)
    if (sc4[k] >= THRESH) { cmask |= (1u << k); ccount++; }
  uint32_t total;
  uint32_t p = blockscan(ccount, wsum, tid, &total);
  if (tid == 0) cnt_blk[blockIdx.x] = total;  // TRUE count (k_rank detects >CAP)
  unsigned long long* dst = keys_raw + (size_t)blockIdx.x * CAP;
#pragma unroll
  for (int k = 0; k < 4; ++k) {
    if (cmask & (1u << k)) {
      if (p < (uint32_t)CAP) {
        int i = (blk << 10) + (tid << 2) + k;
        dst[p] = ((unsigned long long)(~__float_as_uint(sc4[k])) << 32) | (uint32_t)i;
      }
      p++;
    }
  }
}

// gather per-block counts -> bases; compact keys to LDS; rank-by-counting (broadcast
// windows); decode+write sorted boxes/levels; publish ctrs; zero cnt2 + ticket.
__global__ __launch_bounds__(256) void k_rank(const uint32_t* __restrict__ cnt_blk,
                                              const unsigned long long* __restrict__ keys_raw,
                                              const float4* __restrict__ deltas4,
                                              const float4* __restrict__ anchors4,
                                              const float* __restrict__ im_info,
                                              const int* __restrict__ ids,
                                              uint32_t* ctrs,
                                              float4* sboxes, int* slev,
                                              uint32_t* cnt2) {
  const int b = blockIdx.y;
  const int r = blockIdx.x;            // 0..31: owns candidates [r*64, r*64+64)
  const int tid = threadIdx.x;
  const int lane = tid & 63, wid = tid >> 6;
  __shared__ unsigned long long sk[MMAX];   // 16 KB
  __shared__ uint32_t scnt[64], sbs[64];
  __shared__ uint32_t psum[256];
  __shared__ uint32_t meta[2];              // [0]=n_capped_sum [1]=ovflag

  if (tid < 64) {
    uint32_t c = cnt_blk[b * 64 + tid];
    uint32_t cc = min(c, (uint32_t)CAP);
    scnt[tid] = cc;
    uint32_t x = cc;
    for (int off = 1; off < 64; off <<= 1) {
      uint32_t u = __shfl_up(x, off, 64);
      if (lane >= off) x += u;
    }
    sbs[tid] = x - cc;
    unsigned long long ov = __ballot(c > (uint32_t)CAP);
    if (tid == 63) { meta[0] = x; meta[1] = (ov != 0ULL) ? 1u : 0u; }
  }
  __syncthreads();
  uint32_t nsum = meta[0];
  int n = min((int)nsum, MMAX);
  uint32_t flag = meta[1] | ((nsum > (uint32_t)MMAX) ? 1u : 0u);
  if (r == 0 && tid == 0) {
    ctrs[b] = (uint32_t)n;
    ctrs[8 + b] = flag;
    ctrs[12 + b] = 0u;   // ticket counter for k_po (prior dispatch -> race-free)
  }
  if (tid < 64) cnt2[(size_t)b * MMAX + r * 64 + tid] = 0u;  // 32 blocks x 64 = MMAX
  // compact: thread group of 4 per source block
  {
    int k = tid >> 2, q = tid & 3;
    uint32_t cb = sbs[k], cc = scnt[k];
    const unsigned long long* src = keys_raw + ((size_t)b * 64 + k) * CAP;
    for (uint32_t o = q; o < cc; o += 4) {
      uint32_t d = cb + o;
      if (d < (uint32_t)MMAX) sk[d] = src[o];
    }
  }
  for (int i = tid; i < MMAX; i += 256) if (i >= n) sk[i] = ~0ULL;
  __syncthreads();
  // rank my 64 candidates: each wave counts one 512-key window (broadcast reads)
  int c = r * 64 + lane;
  uint32_t partial = 0;
  if (c < n) {
    unsigned long long myk = sk[c];
    const ulonglong2* p2 = (const ulonglong2*)(sk + (size_t)wid * 512);
    for (int it = 0; it < 256; it += 4) {
      ulonglong2 a = p2[it], bq = p2[it + 1], cq = p2[it + 2], dq = p2[it + 3];
      partial += (uint32_t)(a.x < myk) + (uint32_t)(a.y < myk) +
                 (uint32_t)(bq.x < myk) + (uint32_t)(bq.y < myk) +
                 (uint32_t)(cq.x < myk) + (uint32_t)(cq.y < myk) +
                 (uint32_t)(dq.x < myk) + (uint32_t)(dq.y < myk);
    }
  }
  psum[wid * 64 + lane] = partial;
  __syncthreads();
  if (tid < 64) {
    int cc = r * 64 + tid;
    if (cc < n) {
      uint32_t rank = psum[tid] + psum[64 + tid] + psum[128 + tid] + psum[192 + tid];
      if (rank < (uint32_t)MMAX) {
        unsigned long long key = sk[cc];
        int i = (int)(uint32_t)key;
        float wmax = im_info[b * 3 + 1] - 1.0f;
        float hmax = im_info[b * 3 + 0] - 1.0f;
        float x1, y1, x2, y2;
        decode_box(anchors4, deltas4, b, i, wmax, hmax, x1, y1, x2, y2);
        sboxes[(size_t)b * MMAX + rank] = make_float4(x1, y1, x2, y2);
        slev[(size_t)b * MMAX + rank] = ids[i];
      }
    }
  }
}

// 1024-thread (16-wave) scan
__device__ __forceinline__ uint32_t scan_pair(uint32_t pairsum, volatile uint32_t* wsum,
                                              int tid, uint32_t* total_out) {
  int lane = tid & 63, wid = tid >> 6;
  uint32_t v = pairsum;
  for (int off = 1; off < 64; off <<= 1) {
    uint32_t u = __shfl_up(v, off, 64);
    if (lane >= off) v += u;
  }
  if (lane == 63) wsum[wid] = v;
  __syncthreads();
  if (tid == 0) {
    uint32_t run = 0;
    for (int w = 0; w < 16; ++w) { uint32_t t = wsum[w]; wsum[w] = run; run += t; }
    wsum[16] = run;
  }
  __syncthreads();
  uint32_t incl = v + wsum[wid];
  *total_out = wsum[16];
  return incl - pairsum;
}

// fused pairs + (tail-block) resolve/output/fallback.
// 33 blocks/image x 1024 threads; wave w handles tile blkL*16+w; last block to
// finish its image (release-acquire ticket, ONE per block) performs the k_out body.
__global__ __launch_bounds__(1024) void k_po(const float* __restrict__ scores,
                                             const float4* __restrict__ deltas4,
                                             const float4* __restrict__ anchors4,
                                             const float* __restrict__ im_info,
                                             const int* __restrict__ ids,
                                             uint32_t* ctrs,
                                             const float4* __restrict__ sboxes,
                                             const int* __restrict__ slev,
                                             uint32_t* cnt2, int* suplist,
                                             float* __restrict__ out) {
  const int b = blockIdx.y;
  const int blkL = blockIdx.x;     // 0..32
  const int tid = threadIdx.x;
  const int lane = tid & 63, wid = tid >> 6;
  __shared__ float4 ib[16][64];    // per-wave I-tiles
  __shared__ int il[16][64];
  __shared__ int swin;
  int n = min((int)ctrs[b], MMAX);

  // ---------- pairs phase (tile body verbatim; one tile per wave) ----------
  {
    int p = blkL * 16 + wid;       // 0..527
    int tj = (int)((sqrtf(8.0f * (float)p + 1.0f) - 1.0f) * 0.5f);
    while ((tj + 1) * (tj + 2) / 2 <= p) ++tj;
    while (tj * (tj + 1) / 2 > p) --tj;
    int ti = p - tj * (tj + 1) / 2;
    bool act = (tj * 64 < n);
    int ii = ti * 64 + lane;
    if (act && ii < n) {
      ib[wid][lane] = sboxes[(size_t)b * MMAX + ii];
      il[wid][lane] = slev[(size_t)b * MMAX + ii];
    } else {
      il[wid][lane] = -1;
    }
    int j = tj * 64 + lane;
    float4 J = make_float4(0.f, 0.f, 0.f, 0.f);
    int jl = -2;
    float aj = 0.0f;
    if (act && j < n) {
      J = sboxes[(size_t)b * MMAX + j];
      jl = slev[(size_t)b * MMAX + j];
      aj = (J.z - J.x) * (J.w - J.y);
    }
    __syncthreads();
    if (act && j < n) {
      int imax = (ti == tj) ? lane : 64;  // diagonal: only i<j
      for (int k = 0; k < imax; ++k) {
        if (il[wid][k] != jl) continue;
        float4 I = ib[wid][k];
        float xx1 = fmaxf(I.x, J.x), yy1 = fmaxf(I.y, J.y);
        float xx2 = fminf(I.z, J.z), yy2 = fminf(I.w, J.w);
        float inter = fmaxf(xx2 - xx1, 0.0f) * fmaxf(yy2 - yy1, 0.0f);
        float ai = (I.z - I.x) * (I.w - I.y);
        float iou = inter / fmaxf((ai + aj) - inter, 1e-6f);
        if (iou > NMS_T) {
          uint32_t s = atomicAdd(&cnt2[(size_t)b * MMAX + j], 1u);
          if (s < (uint32_t)KSUP) suplist[((size_t)b * MMAX + j) * KSUP + s] = ti * 64 + k;
          else atomicOr(&ctrs[8 + b], 1u);  // suppressor-list overflow -> fallback
        }
      }
    }
  }

  // ---------- ticket: ONE release-acquire RMW per block (no per-thread fences).
  // __syncthreads() drains each wave's vmcnt, so all block writes are in this
  // XCD's L2; the ACQ_REL agent-scope RMW by tid==0 emits a single L2
  // writeback (release) + invalidate (acquire) covering them.
  __syncthreads();
  if (tid == 0) {
    uint32_t old = __hip_atomic_fetch_add(&ctrs[12 + b], 1u,
                                          __ATOMIC_ACQ_REL, __HIP_MEMORY_SCOPE_AGENT);
    swin = (old == (uint32_t)(PBLK - 1)) ? 1 : 0;
  }
  __syncthreads();
  if (!swin) return;

  // ---------- k_out body (verbatim; cross-block data via agent atomic loads) ----------
  __shared__ uint8_t kept[MMAX];
  __shared__ uint32_t wsum[17];
  __shared__ uint16_t unc[UNC];
  __shared__ int supld[UNC][KSUP];
  __shared__ uint8_t supn[UNC];
  int j0 = tid * 2, j1 = tid * 2 + 1;
  uint32_t c0 = (j0 < n) ? __hip_atomic_load(&cnt2[(size_t)b * MMAX + j0],
                                             __ATOMIC_RELAXED, __HIP_MEMORY_SCOPE_AGENT) : 0u;
  uint32_t c1 = (j1 < n) ? __hip_atomic_load(&cnt2[(size_t)b * MMAX + j1],
                                             __ATOMIC_RELAXED, __HIP_MEMORY_SCOPE_AGENT) : 0u;
  kept[j0] = (j0 < n && c0 == 0u) ? 1 : 0;
  kept[j1] = (j1 < n && c1 == 0u) ? 1 : 0;
  uint32_t u0 = (j0 < n && c0 > 0u) ? 1u : 0u;
  uint32_t u1 = (j1 < n && c1 > 0u) ? 1u : 0u;
  uint32_t tot_unc;
  uint32_t base = scan_pair(u0 + u1, wsum, tid, &tot_unc);
  if (u0) {
    uint32_t p = base;
    if (p < UNC) {
      int m = (int)min(c0, (uint32_t)KSUP);
      unc[p] = (uint16_t)j0; supn[p] = (uint8_t)m;
      for (int s = 0; s < m; ++s)
        supld[p][s] = __hip_atomic_load(&suplist[((size_t)b * MMAX + j0) * KSUP + s],
                                        __ATOMIC_RELAXED, __HIP_MEMORY_SCOPE_AGENT);
    }
  }
  if (u1) {
    uint32_t p = base + u0;
    if (p < UNC) {
      int m = (int)min(c1, (uint32_t)KSUP);
      unc[p] = (uint16_t)j1; supn[p] = (uint8_t)m;
      for (int s = 0; s < m; ++s)
        supld[p][s] = __hip_atomic_load(&suplist[((size_t)b * MMAX + j1) * KSUP + s],
                                        __ATOMIC_RELAXED, __HIP_MEMORY_SCOPE_AGENT);
    }
  }
  __syncthreads();
  if (tid < 64) {  // wave 0: exact greedy resolution in ascending rank order
    int nu = (int)min(tot_unc, (uint32_t)UNC);
    for (int u = 0; u < nu; ++u) {
      int m = (int)supn[u];
      int pred = (tid < m) ? (int)kept[supld[u][tid]] : 0;
      unsigned long long bal = __ballot(pred);
      if (tid == 0) kept[unc[u]] = (bal == 0ULL) ? 1 : 0;
    }
  }
  __syncthreads();
  uint32_t k0 = kept[j0], k1 = kept[j1];
  uint32_t total;
  uint32_t pbase = scan_pair(k0 + k1, wsum, tid, &total);
  if (k0 && pbase < (uint32_t)TOPN) {
    float4 bx = sboxes[(size_t)b * MMAX + j0];
    size_t o = ((size_t)b * TOPN + pbase) * 5;
    out[o] = (float)b; out[o+1] = bx.x; out[o+2] = bx.y; out[o+3] = bx.z; out[o+4] = bx.w;
  }
  if (k1) {
    uint32_t p = pbase + k0;
    if (p < (uint32_t)TOPN) {
      float4 bx = sboxes[(size_t)b * MMAX + j1];
      size_t o = ((size_t)b * TOPN + p) * 5;
      out[o] = (float)b; out[o+1] = bx.x; out[o+2] = bx.y; out[o+3] = bx.z; out[o+4] = bx.w;
    }
  }
  for (int t = tid; t < TOPN; t += 1024) {
    if ((uint32_t)t >= total) {
      size_t o = ((size_t)b * TOPN + t) * 5;
      out[o] = (float)b; out[o+1] = 0.0f; out[o+2] = 0.0f; out[o+3] = 0.0f; out[o+4] = 0.0f;
    }
  }

  uint32_t gflag = __hip_atomic_load(&ctrs[8 + b], __ATOMIC_RELAXED, __HIP_MEMORY_SCOPE_AGENT);
  bool needFB = (gflag != 0u) || (total < (uint32_t)TOPN) || (tot_unc > (uint32_t)UNC);
  if (!needFB) return;

  // ---------- exact brute-force fallback (block-uniform path) ----------
  __shared__ uint32_t mask[NB / 32];
  __shared__ float rv[1024];
  __shared__ int ri[1024];
  __shared__ float fm[16];
  const float wmax = im_info[b * 3 + 1] - 1.0f;
  const float hmax = im_info[b * 3 + 0] - 1.0f;
  __syncthreads();
  float mx = 0.0f;
  for (int i = tid; i < NB; i += 1024) {
    float x1, y1, x2, y2;
    decode_box(anchors4, deltas4, b, i, wmax, hmax, x1, y1, x2, y2);
    mx = fmaxf(mx, fmaxf(fmaxf(x1, y1), fmaxf(x2, y2)));
  }
  for (int o = 32; o > 0; o >>= 1) mx = fmaxf(mx, __shfl_xor(mx, o, 64));
  if ((tid & 63) == 0) fm[tid >> 6] = mx;
  __syncthreads();
  if (tid == 0) {
    float m = fm[0];
    for (int w = 1; w < 16; ++w) m = fmaxf(m, fm[w]);
    fm[0] = m;
  }
  for (int i = tid; i < NB / 32; i += 1024) mask[i] = 0u;
  __syncthreads();
  float max_c = fm[0] + 1.0f;
  for (int it = 0; it < TOPN; ++it) {
    float bv = -3e38f; int bi = 0x7fffffff;
    for (int i = tid; i < NB; i += 1024) {
      bool sup = (mask[i >> 5] >> (i & 31)) & 1u;
      float v = sup ? NEGV : scores[(size_t)b * NB + i];
      if (v > bv || (v == bv && i < bi)) { bv = v; bi = i; }
    }
    rv[tid] = bv; ri[tid] = bi;
    __syncthreads();
    for (int s = 512; s > 0; s >>= 1) {
      if (tid < s) {
        float v2 = rv[tid + s]; int i2 = ri[tid + s];
        if (v2 > rv[tid] || (v2 == rv[tid] && i2 < ri[tid])) { rv[tid] = v2; ri[tid] = i2; }
      }
      __syncthreads();
    }
    int ii = ri[0]; float vv = rv[0];
    bool valid = vv > NEGV * 0.5f;
    if (!valid) {
      if (tid == 0) {
        size_t o = ((size_t)b * TOPN + it) * 5;
        out[o] = (float)b; out[o+1] = 0; out[o+2] = 0; out[o+3] = 0; out[o+4] = 0;
      }
      __syncthreads();
      continue;
    }
    float x1, y1, x2, y2;
    decode_box(anchors4, deltas4, b, ii, wmax, hmax, x1, y1, x2, y2);
    int lv = ids[ii];
    float off = (float)lv * max_c;
    float s0 = x1 + off, s1 = y1 + off, s2 = x2 + off, s3 = y2 + off;
    float a1 = (s2 - s0) * (s3 - s1);
    if (tid == 0) {
      size_t o = ((size_t)b * TOPN + it) * 5;
      out[o] = (float)b; out[o+1] = x1; out[o+2] = y1; out[o+3] = x2; out[o+4] = y2;
    }
    for (int j = tid; j < NB; j += 1024) {
      if ((mask[j >> 5] >> (j & 31)) & 1u) continue;
      if (ids[j] != lv) continue;  // cross-level IoU exactly 0 under offset geometry
      float bx1, by1, bx2, by2;
      decode_box(anchors4, deltas4, b, j, wmax, hmax, bx1, by1, bx2, by2);
      float t0 = bx1 + off, t1 = by1 + off, t2 = bx2 + off, t3 = by2 + off;
      float xx1 = fmaxf(s0, t0), yy1 = fmaxf(s1, t1);
      float xx2 = fminf(s2, t2), yy2 = fminf(s3, t3);
      float inter = fmaxf(xx2 - xx1, 0.0f) * fmaxf(yy2 - yy1, 0.0f);
      float a2r = (t2 - t0) * (t3 - t1);
      float iou = inter / fmaxf(a1 + a2r - inter, 1e-6f);
      if (iou > NMS_T) atomicOr(&mask[j >> 5], 1u << (j & 31));
    }
    if (tid == 0) atomicOr(&mask[ii >> 5], 1u << (ii & 31));
    __syncthreads();
  }
}

extern "C" void kernel_launch(void* const* d_in, const int* in_sizes, int n_in,
                              void* d_out, int out_size, void* d_ws, size_t ws_size,
                              hipStream_t stream) {
  const float*  scores   = (const float*)d_in[0];
  const float4* deltas4  = (const float4*)d_in[1];
  const float4* anchors4 = (const float4*)d_in[2];
  const float*  im_info  = (const float*)d_in[3];
  const int*    ids      = (const int*)d_in[4];
  float* out = (float*)d_out;

  char* ws = (char*)d_ws;
  uint32_t*           ctrs     = (uint32_t*)ws;
  uint32_t*           cnt_blk  = (uint32_t*)(ws + OFF_CBLK);
  unsigned long long* keys_raw = (unsigned long long*)(ws + OFF_KRAW);
  float4*             sboxes   = (float4*)(ws + OFF_SBOX);
  int*                slev     = (int*)(ws + OFF_SLEV);
  uint32_t*           cnt2     = (uint32_t*)(ws + OFF_CNT2);
  int*                suplist  = (int*)(ws + OFF_SUP);

  hipLaunchKernelGGL(k_prep, dim3(64 * BATCH), dim3(256), 0, stream,
                     scores, keys_raw, cnt_blk);
  hipLaunchKernelGGL(k_rank, dim3(NTILE, BATCH), dim3(256), 0, stream,
                     cnt_blk, keys_raw, deltas4, anchors4, im_info, ids,
                     ctrs, sboxes, slev, cnt2);
  hipLaunchKernelGGL(k_po, dim3(PBLK, BATCH), dim3(1024), 0, stream,
                     scores, deltas4, anchors4, im_info, ids, ctrs,
                     sboxes, slev, cnt2, suplist, out);
}

// Round 9
// 100.397 us; speedup vs baseline: 1.2805x; 1.0372x over previous
//
#include <hip/hip_runtime.h>
#include <stdint.h>

#define NB     65536
#define BATCH  4
#define TOPN   1000
#define MMAX   2048
#define NTILE  (MMAX / 64)                 // 32
#define NPAIRS (NTILE * (NTILE + 1) / 2)   // 528
#define CAP    128                         // per-prep-block candidate region
#define KSUP   8
#define UNC    128
#define THRESH 0.974f
#define NEGV   (-1e9f)
#define NMS_T  0.7f

// ws layout (bytes):
//   0      : ctrs u32[16] ([0..3]=n, [8..11]=fallback flag)
//   64     : cnt_blk  u32[256]   per prep-block true candidate count
//   1088   : keys_raw u64[256*CAP]
//   263232 : sboxes   float4[B*MMAX]  rank-sorted, clipped, non-offset
//   394304 : slev     i32[B*MMAX]
//   427072 : cnt2     u32[B*MMAX]  per-candidate suppressor counts (zeroed by k_rank)
//   459840 : suplist  i32[B*MMAX*KSUP]
#define OFF_CBLK   64
#define OFF_KRAW   1088
#define OFF_SBOX   263232
#define OFF_SLEV   394304
#define OFF_CNT2   427072
#define OFF_SUP    459840

__device__ __forceinline__ void decode_box(const float4* __restrict__ anchors4,
                                           const float4* __restrict__ deltas4,
                                           int b, int i, float wmax, float hmax,
                                           float& x1, float& y1, float& x2, float& y2) {
  float4 a = anchors4[i];
  float4 d = deltas4[(size_t)b * NB + i];
  float ws = a.z - a.x + 1.0f;
  float hs = a.w - a.y + 1.0f;
  float cx = a.x + 0.5f * ws;
  float cy = a.y + 0.5f * hs;
  float pcx = d.x * ws + cx;
  float pcy = d.y * hs + cy;
  float pw = expf(d.z) * ws;
  float ph = expf(d.w) * hs;
  x1 = pcx - 0.5f * pw; y1 = pcy - 0.5f * ph;
  x2 = pcx + 0.5f * pw; y2 = pcy + 0.5f * ph;
  x1 = fminf(fmaxf(x1, 0.0f), wmax);
  y1 = fminf(fmaxf(y1, 0.0f), hmax);
  x2 = fminf(fmaxf(x2, 0.0f), wmax);
  y2 = fminf(fmaxf(y2, 0.0f), hmax);
}

// block-wide exclusive scan, 256 threads (4 waves). wsum: u32[5].
__device__ __forceinline__ uint32_t blockscan(uint32_t v, volatile uint32_t* wsum,
                                              int tid, uint32_t* total) {
  __syncthreads();
  int lane = tid & 63, wid = tid >> 6;
  uint32_t x = v;
  for (int off = 1; off < 64; off <<= 1) {
    uint32_t u = __shfl_up(x, off, 64);
    if (lane >= off) x += u;
  }
  if (lane == 63) wsum[wid] = x;
  __syncthreads();
  if (tid == 0) {
    uint32_t run = 0;
    for (int w = 0; w < 4; ++w) { uint32_t t = wsum[w]; wsum[w] = run; run += t; }
    wsum[4] = run;
  }
  __syncthreads();
  *total = wsum[4];
  return x - v + wsum[wid];
}

// pure score-threshold scan: float4 loads, per-block private emission (no decode, no atomics)
__global__ __launch_bounds__(256) void k_prep(const float* __restrict__ scores,
                                              unsigned long long* __restrict__ keys_raw,
                                              uint32_t* __restrict__ cnt_blk) {
  const int b = blockIdx.x >> 6;       // 64 blocks / image
  const int blk = blockIdx.x & 63;     // 1024 scores / block
  const int tid = threadIdx.x;
  __shared__ uint32_t wsum[5];
  const float4* s4 = (const float4*)scores + (size_t)b * (NB / 4) + (size_t)blk * 256 + tid;
  float4 s = *s4;
  float sc4[4] = {s.x, s.y, s.z, s.w};
  uint32_t cmask = 0, ccount = 0;
#pragma unroll
  for (int k = 0; k < 4; ++k)
    if (sc4[k] >= THRESH) { cmask |= (1u << k); ccount++; }
  uint32_t total;
  uint32_t p = blockscan(ccount, wsum, tid, &total);
  if (tid == 0) cnt_blk[blockIdx.x] = total;  // TRUE count (k_rank detects >CAP)
  unsigned long long* dst = keys_raw + (size_t)blockIdx.x * CAP;
#pragma unroll
  for (int k = 0; k < 4; ++k) {
    if (cmask & (1u << k)) {
      if (p < (uint32_t)CAP) {
        int i = (blk << 10) + (tid << 2) + k;
        dst[p] = ((unsigned long long)(~__float_as_uint(sc4[k])) << 32) | (uint32_t)i;
      }
      p++;
    }
  }
}

// gather per-block counts -> bases; compact keys to LDS; rank-by-counting (broadcast
// windows); decode+write sorted boxes/levels; publish ctrs; zero cnt2.
__global__ __launch_bounds__(256) void k_rank(const uint32_t* __restrict__ cnt_blk,
                                              const unsigned long long* __restrict__ keys_raw,
                                              const float4* __restrict__ deltas4,
                                              const float4* __restrict__ anchors4,
                                              const float* __restrict__ im_info,
                                              const int* __restrict__ ids,
                                              uint32_t* ctrs,
                                              float4* sboxes, int* slev,
                                              uint32_t* cnt2) {
  const int b = blockIdx.y;
  const int r = blockIdx.x;            // 0..31: owns candidates [r*64, r*64+64)
  const int tid = threadIdx.x;
  const int lane = tid & 63, wid = tid >> 6;
  __shared__ unsigned long long sk[MMAX];   // 16 KB
  __shared__ uint32_t scnt[64], sbs[64];
  __shared__ uint32_t psum[256];
  __shared__ uint32_t meta[2];              // [0]=n_capped_sum [1]=ovflag

  if (tid < 64) {
    uint32_t c = cnt_blk[b * 64 + tid];
    uint32_t cc = min(c, (uint32_t)CAP);
    scnt[tid] = cc;
    uint32_t x = cc;
    for (int off = 1; off < 64; off <<= 1) {
      uint32_t u = __shfl_up(x, off, 64);
      if (lane >= off) x += u;
    }
    sbs[tid] = x - cc;
    unsigned long long ov = __ballot(c > (uint32_t)CAP);
    if (tid == 63) { meta[0] = x; meta[1] = (ov != 0ULL) ? 1u : 0u; }
  }
  __syncthreads();
  uint32_t nsum = meta[0];
  int n = min((int)nsum, MMAX);
  uint32_t flag = meta[1] | ((nsum > (uint32_t)MMAX) ? 1u : 0u);
  if (r == 0 && tid == 0) {
    ctrs[b] = (uint32_t)n;
    ctrs[8 + b] = flag;
  }
  if (tid < 64) cnt2[(size_t)b * MMAX + r * 64 + tid] = 0u;  // 32 blocks x 64 = MMAX
  // compact: thread group of 4 per source block
  {
    int k = tid >> 2, q = tid & 3;
    uint32_t cb = sbs[k], cc = scnt[k];
    const unsigned long long* src = keys_raw + ((size_t)b * 64 + k) * CAP;
    for (uint32_t o = q; o < cc; o += 4) {
      uint32_t d = cb + o;
      if (d < (uint32_t)MMAX) sk[d] = src[o];
    }
  }
  for (int i = tid; i < MMAX; i += 256) if (i >= n) sk[i] = ~0ULL;
  __syncthreads();
  // rank my 64 candidates: each wave counts one 512-key window (broadcast reads)
  int c = r * 64 + lane;
  uint32_t partial = 0;
  if (c < n) {
    unsigned long long myk = sk[c];
    const ulonglong2* p2 = (const ulonglong2*)(sk + (size_t)wid * 512);
    for (int it = 0; it < 256; it += 4) {
      ulonglong2 a = p2[it], bq = p2[it + 1], cq = p2[it + 2], dq = p2[it + 3];
      partial += (uint32_t)(a.x < myk) + (uint32_t)(a.y < myk) +
                 (uint32_t)(bq.x < myk) + (uint32_t)(bq.y < myk) +
                 (uint32_t)(cq.x < myk) + (uint32_t)(cq.y < myk) +
                 (uint32_t)(dq.x < myk) + (uint32_t)(dq.y < myk);
    }
  }
  psum[wid * 64 + lane] = partial;
  __syncthreads();
  if (tid < 64) {
    int cc = r * 64 + tid;
    if (cc < n) {
      uint32_t rank = psum[tid] + psum[64 + tid] + psum[128 + tid] + psum[192 + tid];
      if (rank < (uint32_t)MMAX) {
        unsigned long long key = sk[cc];
        int i = (int)(uint32_t)key;
        float wmax = im_info[b * 3 + 1] - 1.0f;
        float hmax = im_info[b * 3 + 0] - 1.0f;
        float x1, y1, x2, y2;
        decode_box(anchors4, deltas4, b, i, wmax, hmax, x1, y1, x2, y2);
        sboxes[(size_t)b * MMAX + rank] = make_float4(x1, y1, x2, y2);
        slev[(size_t)b * MMAX + rank] = ids[i];
      }
    }
  }
}

// tiled all-pairs potential-suppressor detection. Same-level IoU is translation-
// invariant, so no level offset is needed here (cross-level pairs are skipped;
// they are provably disjoint under the reference's offset).
__global__ __launch_bounds__(64) void k_pairs(uint32_t* ctrs,
                                              const float4* __restrict__ sboxes,
                                              const int* __restrict__ slev,
                                              uint32_t* cnt2, int* suplist) {
  int b = blockIdx.y;
  int p = blockIdx.x;
  int tj = (int)((sqrtf(8.0f * (float)p + 1.0f) - 1.0f) * 0.5f);
  while ((tj + 1) * (tj + 2) / 2 <= p) ++tj;
  while (tj * (tj + 1) / 2 > p) --tj;
  int ti = p - tj * (tj + 1) / 2;
  int n = min((int)ctrs[b], MMAX);
  if (tj * 64 >= n) return;  // uniform across block
  int lane = threadIdx.x;

  __shared__ float4 ib[64];
  __shared__ int il[64];
  int ii = ti * 64 + lane;
  if (ii < n) {
    ib[lane] = sboxes[(size_t)b * MMAX + ii];
    il[lane] = slev[(size_t)b * MMAX + ii];
  } else {
    il[lane] = -1;
  }
  int j = tj * 64 + lane;
  float4 J = make_float4(0.f, 0.f, 0.f, 0.f);
  int jl = -2;
  float aj = 0.0f;
  if (j < n) {
    J = sboxes[(size_t)b * MMAX + j];
    jl = slev[(size_t)b * MMAX + j];
    aj = (J.z - J.x) * (J.w - J.y);
  }
  __syncthreads();
  if (j < n) {
    int imax = (ti == tj) ? lane : 64;  // diagonal: only i<j
    for (int k = 0; k < imax; ++k) {
      if (il[k] != jl) continue;
      float4 I = ib[k];
      float xx1 = fmaxf(I.x, J.x), yy1 = fmaxf(I.y, J.y);
      float xx2 = fminf(I.z, J.z), yy2 = fminf(I.w, J.w);
      float inter = fmaxf(xx2 - xx1, 0.0f) * fmaxf(yy2 - yy1, 0.0f);
      float ai = (I.z - I.x) * (I.w - I.y);
      float iou = inter / fmaxf((ai + aj) - inter, 1e-6f);
      if (iou > NMS_T) {
        uint32_t s = atomicAdd(&cnt2[(size_t)b * MMAX + j], 1u);
        if (s < (uint32_t)KSUP) suplist[((size_t)b * MMAX + j) * KSUP + s] = ti * 64 + k;
        else ctrs[8 + b] = 1u;  // suppressor-list overflow -> fallback
      }
    }
  }
}

// 1024-thread (16-wave) scan
__device__ __forceinline__ uint32_t scan_pair(uint32_t pairsum, volatile uint32_t* wsum,
                                              int tid, uint32_t* total_out) {
  int lane = tid & 63, wid = tid >> 6;
  uint32_t v = pairsum;
  for (int off = 1; off < 64; off <<= 1) {
    uint32_t u = __shfl_up(v, off, 64);
    if (lane >= off) v += u;
  }
  if (lane == 63) wsum[wid] = v;
  __syncthreads();
  if (tid == 0) {
    uint32_t run = 0;
    for (int w = 0; w < 16; ++w) { uint32_t t = wsum[w]; wsum[w] = run; run += t; }
    wsum[16] = run;
  }
  __syncthreads();
  uint32_t incl = v + wsum[wid];
  *total_out = wsum[16];
  return incl - pairsum;
}

// exact ordered resolution + compaction + output, with inline exact brute-force
// fallback (offset arithmetic exactly as reference) when any overflow occurred.
__global__ __launch_bounds__(1024) void k_out(const float* __restrict__ scores,
                                              const float4* __restrict__ deltas4,
                                              const float4* __restrict__ anchors4,
                                              const float* __restrict__ im_info,
                                              const int* __restrict__ ids,
                                              const uint32_t* __restrict__ ctrs,
                                              const uint32_t* __restrict__ cnt2,
                                              const int* __restrict__ suplist,
                                              const float4* __restrict__ sboxes,
                                              float* __restrict__ out) {
  int b = blockIdx.x;
  int tid = threadIdx.x;
  __shared__ uint8_t kept[MMAX];
  __shared__ uint32_t wsum[17];
  __shared__ uint16_t unc[UNC];
  __shared__ int supld[UNC][KSUP];
  __shared__ uint8_t supn[UNC];
  int n = min((int)ctrs[b], MMAX);
  int j0 = tid * 2, j1 = tid * 2 + 1;
  uint32_t c0 = (j0 < n) ? cnt2[(size_t)b * MMAX + j0] : 0u;
  uint32_t c1 = (j1 < n) ? cnt2[(size_t)b * MMAX + j1] : 0u;
  kept[j0] = (j0 < n && c0 == 0u) ? 1 : 0;
  kept[j1] = (j1 < n && c1 == 0u) ? 1 : 0;
  uint32_t u0 = (j0 < n && c0 > 0u) ? 1u : 0u;
  uint32_t u1 = (j1 < n && c1 > 0u) ? 1u : 0u;
  uint32_t tot_unc;
  uint32_t base = scan_pair(u0 + u1, wsum, tid, &tot_unc);
  if (u0) {
    uint32_t p = base;
    if (p < UNC) {
      int m = (int)min(c0, (uint32_t)KSUP);
      unc[p] = (uint16_t)j0; supn[p] = (uint8_t)m;
      for (int s = 0; s < m; ++s) supld[p][s] = suplist[((size_t)b * MMAX + j0) * KSUP + s];
    }
  }
  if (u1) {
    uint32_t p = base + u0;
    if (p < UNC) {
      int m = (int)min(c1, (uint32_t)KSUP);
      unc[p] = (uint16_t)j1; supn[p] = (uint8_t)m;
      for (int s = 0; s < m; ++s) supld[p][s] = suplist[((size_t)b * MMAX + j1) * KSUP + s];
    }
  }
  __syncthreads();
  if (tid < 64) {  // wave 0: exact greedy resolution in ascending rank order
    int nu = (int)min(tot_unc, (uint32_t)UNC);
    for (int u = 0; u < nu; ++u) {
      int m = (int)supn[u];
      int pred = (tid < m) ? (int)kept[supld[u][tid]] : 0;
      unsigned long long bal = __ballot(pred);
      if (tid == 0) kept[unc[u]] = (bal == 0ULL) ? 1 : 0;
    }
  }
  __syncthreads();
  uint32_t k0 = kept[j0], k1 = kept[j1];
  uint32_t total;
  uint32_t pbase = scan_pair(k0 + k1, wsum, tid, &total);
  if (k0 && pbase < (uint32_t)TOPN) {
    float4 bx = sboxes[(size_t)b * MMAX + j0];
    size_t o = ((size_t)b * TOPN + pbase) * 5;
    out[o] = (float)b; out[o+1] = bx.x; out[o+2] = bx.y; out[o+3] = bx.z; out[o+4] = bx.w;
  }
  if (k1) {
    uint32_t p = pbase + k0;
    if (p < (uint32_t)TOPN) {
      float4 bx = sboxes[(size_t)b * MMAX + j1];
      size_t o = ((size_t)b * TOPN + p) * 5;
      out[o] = (float)b; out[o+1] = bx.x; out[o+2] = bx.y; out[o+3] = bx.z; out[o+4] = bx.w;
    }
  }
  for (int t = tid; t < TOPN; t += 1024) {
    if ((uint32_t)t >= total) {
      size_t o = ((size_t)b * TOPN + t) * 5;
      out[o] = (float)b; out[o+1] = 0.0f; out[o+2] = 0.0f; out[o+3] = 0.0f; out[o+4] = 0.0f;
    }
  }

  bool needFB = (ctrs[8 + b] != 0u) || (total < (uint32_t)TOPN) || (tot_unc > (uint32_t)UNC);
  if (!needFB) return;

  // ---------- exact brute-force fallback (block-uniform path) ----------
  __shared__ uint32_t mask[NB / 32];
  __shared__ float rv[1024];
  __shared__ int ri[1024];
  __shared__ float fm[16];
  const float wmax = im_info[b * 3 + 1] - 1.0f;
  const float hmax = im_info[b * 3 + 0] - 1.0f;
  __syncthreads();  // order resolve-phase out writes before overwrite
  // exact max over all clipped coords (matches jnp.max(boxes))
  float mx = 0.0f;
  for (int i = tid; i < NB; i += 1024) {
    float x1, y1, x2, y2;
    decode_box(anchors4, deltas4, b, i, wmax, hmax, x1, y1, x2, y2);
    mx = fmaxf(mx, fmaxf(fmaxf(x1, y1), fmaxf(x2, y2)));
  }
  for (int o = 32; o > 0; o >>= 1) mx = fmaxf(mx, __shfl_xor(mx, o, 64));
  if ((tid & 63) == 0) fm[tid >> 6] = mx;
  __syncthreads();
  if (tid == 0) {
    float m = fm[0];
    for (int w = 1; w < 16; ++w) m = fmaxf(m, fm[w]);
    fm[0] = m;
  }
  for (int i = tid; i < NB / 32; i += 1024) mask[i] = 0u;
  __syncthreads();
  float max_c = fm[0] + 1.0f;
  for (int it = 0; it < TOPN; ++it) {
    float bv = -3e38f; int bi = 0x7fffffff;
    for (int i = tid; i < NB; i += 1024) {
      bool sup = (mask[i >> 5] >> (i & 31)) & 1u;
      float v = sup ? NEGV : scores[(size_t)b * NB + i];
      if (v > bv || (v == bv && i < bi)) { bv = v; bi = i; }
    }
    rv[tid] = bv; ri[tid] = bi;
    __syncthreads();
    for (int s = 512; s > 0; s >>= 1) {
      if (tid < s) {
        float v2 = rv[tid + s]; int i2 = ri[tid + s];
        if (v2 > rv[tid] || (v2 == rv[tid] && i2 < ri[tid])) { rv[tid] = v2; ri[tid] = i2; }
      }
      __syncthreads();
    }
    int ii = ri[0]; float vv = rv[0];
    bool valid = vv > NEGV * 0.5f;
    if (!valid) {
      if (tid == 0) {
        size_t o = ((size_t)b * TOPN + it) * 5;
        out[o] = (float)b; out[o+1] = 0; out[o+2] = 0; out[o+3] = 0; out[o+4] = 0;
      }
      __syncthreads();
      continue;
    }
    float x1, y1, x2, y2;
    decode_box(anchors4, deltas4, b, ii, wmax, hmax, x1, y1, x2, y2);
    int lv = ids[ii];
    float off = (float)lv * max_c;
    float s0 = x1 + off, s1 = y1 + off, s2 = x2 + off, s3 = y2 + off;
    float a1 = (s2 - s0) * (s3 - s1);
    if (tid == 0) {
      size_t o = ((size_t)b * TOPN + it) * 5;
      out[o] = (float)b; out[o+1] = x1; out[o+2] = y1; out[o+3] = x2; out[o+4] = y2;
    }
    for (int j = tid; j < NB; j += 1024) {
      if ((mask[j >> 5] >> (j & 31)) & 1u) continue;
      if (ids[j] != lv) continue;  // cross-level IoU exactly 0 under offset geometry
      float bx1, by1, bx2, by2;
      decode_box(anchors4, deltas4, b, j, wmax, hmax, bx1, by1, bx2, by2);
      float t0 = bx1 + off, t1 = by1 + off, t2 = bx2 + off, t3 = by2 + off;
      float xx1 = fmaxf(s0, t0), yy1 = fmaxf(s1, t1);
      float xx2 = fminf(s2, t2), yy2 = fminf(s3, t3);
      float inter = fmaxf(xx2 - xx1, 0.0f) * fmaxf(yy2 - yy1, 0.0f);
      float a2r = (t2 - t0) * (t3 - t1);
      float iou = inter / fmaxf(a1 + a2r - inter, 1e-6f);
      if (iou > NMS_T) atomicOr(&mask[j >> 5], 1u << (j & 31));
    }
    if (tid == 0) atomicOr(&mask[ii >> 5], 1u << (ii & 31));
    __syncthreads();
  }
}

extern "C" void kernel_launch(void* const* d_in, const int* in_sizes, int n_in,
                              void* d_out, int out_size, void* d_ws, size_t ws_size,
                              hipStream_t stream) {
  const float*  scores   = (const float*)d_in[0];
  const float4* deltas4  = (const float4*)d_in[1];
  const float4* anchors4 = (const float4*)d_in[2];
  const float*  im_info  = (const float*)d_in[3];
  const int*    ids      = (const int*)d_in[4];
  float* out = (float*)d_out;

  char* ws = (char*)d_ws;
  uint32_t*           ctrs     = (uint32_t*)ws;
  uint32_t*           cnt_blk  = (uint32_t*)(ws + OFF_CBLK);
  unsigned long long* keys_raw = (unsigned long long*)(ws + OFF_KRAW);
  float4*             sboxes   = (float4*)(ws + OFF_SBOX);
  int*                slev     = (int*)(ws + OFF_SLEV);
  uint32_t*           cnt2     = (uint32_t*)(ws + OFF_CNT2);
  int*                suplist  = (int*)(ws + OFF_SUP);

  hipLaunchKernelGGL(k_prep, dim3(64 * BATCH), dim3(256), 0, stream,
                     scores, keys_raw, cnt_blk);
  hipLaunchKernelGGL(k_rank, dim3(NTILE, BATCH), dim3(256), 0, stream,
                     cnt_blk, keys_raw, deltas4, anchors4, im_info, ids,
                     ctrs, sboxes, slev, cnt2);
  hipLaunchKernelGGL(k_pairs, dim3(NPAIRS, BATCH), dim3(64), 0, stream,
                     ctrs, sboxes, slev, cnt2, suplist);
  hipLaunchKernelGGL(k_out, dim3(BATCH), dim3(1024), 0, stream,
                     scores, deltas4, anchors4, im_info, ids, ctrs, cnt2, suplist,
                     sboxes, out);
}